// Round 8
// baseline (425.677 us; speedup 1.0000x reference)
//
#include <hip/hip_runtime.h>
#include <stdint.h>

#define D_MODEL 1024
#define D_STATE 16
#define D_INNER 2048
#define BATCH   4
#define SEQ     2048
#define ML      (BATCH*SEQ)   // 8192 rows
#define CH      128
#define NCHUNK  (SEQ/CH)      // 16
#define KSEG    8             // K-split for B/C projection GEMM

typedef unsigned short u16;
typedef u16   u16x8  __attribute__((ext_vector_type(8)));
typedef short s16x8  __attribute__((ext_vector_type(8)));
typedef float f32x4  __attribute__((ext_vector_type(4)));

__device__ __forceinline__ float b2f(u16 u){
  union { uint32_t i; float f; } v; v.i = ((uint32_t)u) << 16; return v.f;
}
__device__ __forceinline__ u16 f2b(float f){
  uint32_t x = __float_as_uint(f);
  return (u16)((x + 0x7fffu + ((x >> 16) & 1u)) >> 16);   // RNE
}
__device__ __forceinline__ float silu_f(float v){
  return v / (1.f + __expf(-v));
}
// async global->LDS, 16 B per lane; lds base must be wave-uniform (lane i lands at base + i*16)
__device__ __forceinline__ void gl_lds16(const void* gp, void* lp){
  __builtin_amdgcn_global_load_lds(
      (const __attribute__((address_space(1))) void*)gp,
      (__attribute__((address_space(3))) void*)lp, 16, 0, 0);
}

// ------------- fused prep: W_in^T, W_out^T, cast(x), Wt_bc — one launch -------------
// blocks [0,4096): W_in transpose (R=1024,C=4096); [4096,6144): W_out transpose
// (R=2048,C=1024); [6144,10240): cast x; [10240,10496): bc_wt.
__global__ __launch_bounds__(256) void prep_k(const float* __restrict__ W_in,
                                              const float* __restrict__ W_out,
                                              const float* __restrict__ x,
                                              const float* __restrict__ W_B,
                                              const float* __restrict__ W_C,
                                              u16* __restrict__ Wt_in,
                                              u16* __restrict__ Wt_out,
                                              u16* __restrict__ xbf,
                                              u16* __restrict__ Wt_bc){
  __shared__ float tile[32][33];
  int bb = blockIdx.x;
  if (bb < 6144) {
    const float* in; u16* out; int R, C, bx, by;
    if (bb < 4096) { in = W_in;  out = Wt_in;  R = 1024; C = 4096;
                     bx = (bb & 127) * 32; by = (bb >> 7) * 32; }
    else { bb -= 4096; in = W_out; out = Wt_out; R = 2048; C = 1024;
                     bx = (bb & 31) * 32; by = (bb >> 5) * 32; }
    int tx = threadIdx.x & 31, ty = threadIdx.x >> 5;
    #pragma unroll
    for (int i = 0; i < 32; i += 8)
      tile[ty + i][tx] = in[(size_t)(by + ty + i) * C + bx + tx];
    __syncthreads();
    #pragma unroll
    for (int i = 0; i < 32; i += 8)
      out[(size_t)(bx + ty + i) * R + by + tx] = f2b(tile[tx][ty + i]);
  } else if (bb < 10240) {
    bb -= 6144;
    size_t i = ((size_t)bb * 256 + threadIdx.x) * 8;
    f32x4 a = *(const f32x4*)(x + i);
    f32x4 b = *(const f32x4*)(x + i + 4);
    u16x8 o;
    #pragma unroll
    for (int j = 0; j < 4; ++j){ o[j] = f2b(a[j]); o[4+j] = f2b(b[j]); }
    *(u16x8*)(xbf + i) = o;
  } else {
    bb -= 10240;
    int n = bb >> 3;                         // 0..31
    int k = (bb & 7) * 256 + threadIdx.x;    // 0..2047
    const float* src = (n < 16) ? W_B : W_C;
    Wt_bc[(size_t)n * D_INNER + k] = f2b(src[(size_t)k * 16 + (n & 15)]);
  }
}

// ================= 4-phase 256x256 GEMM for in_proj (deep A-prefetch) =================
// M=8192, N=4096, K=1024. 512 threads = 8 waves (2M x 4N), per-wave output 128x64.
// Full-line staging (8 rows x 128B per gl_lds16) with involutive chunk-XOR; conflicts=0
// verified R4-R7. R7 theory: A was staged only 3 phases (~600cy) before its vmcnt
// consumption — under HBM-miss latency (~900cy). This version stages A(t+2) at p3 (4
// phases ahead, like B), behind a new barrier that makes all waves' A(t)-reads drained.
// DMA issue order per tile: B0(t+2)@p1, B1(t+2)@p2, A(t+2)@p3 -> at p3(t) outstanding =
// B(t+1)[4] A(t+1)[4] B(t+2)[4]; vmcnt(4) drains exactly B(t+1)+A(t+1). RACE RULES (R1):
// vmcnt drains only OWN DMAs -> cross-wave LDS reads sit after {all waves drained +
// s_barrier}; every stage-over-slot separated from all waves' last-read drain by a barrier.
#define G1_K  1024
#define G1_NT (G1_K/64)   // 16 K-tiles

__global__ __launch_bounds__(512, 2) void gemm1_k(const u16* __restrict__ A,
                                                  const u16* __restrict__ Bt,
                                                  const float* __restrict__ bias,
                                                  u16* __restrict__ out0,
                                                  u16* __restrict__ out1){
  __shared__ __align__(16) u16 ldsAll[256*264];  // 135168 B; staging uses first 128 KB,
  u16* ldsA = ldsAll;                            // epilogue reuses full array (pad 264)
  u16* ldsB = ldsAll + 4*8192;

  const int bid = blockIdx.x;
  const int xcd = bid & 7, t2 = bid >> 3;
  const int n0 = (xcd*2 + (t2 & 1)) * 256;     // 16 n-blocks, 2 per XCD
  const int m0 = (t2 >> 1) * 256;              // 32 m-blocks

  const int tid  = threadIdx.x;
  const int wave = tid >> 6, lane = tid & 63;
  const int wr = wave >> 2;                    // 0..1: M half
  const int wc = wave & 3;                     // 0..3: N quarter
  const int lrow = lane & 15;
  const int q    = lane >> 4;                  // 0..3

  // per-lane swizzled read cols (u16): kk=0 and kk=1; (c^4)*8 == c*8 ^ 32
  const int cx0  = ((q ^ (lrow & 7)) << 3);
  const int cx1  = cx0 ^ 32;
  const int arow = lrow * 64;

  // staging: one gl_lds16 = 8 rows x 128B (full lines), source col pre-swizzled
  const int srow = lane >> 3;                          // 0..7
  const int scol = (((lane & 7) ^ (lane >> 3)) << 3);  // swizzled 16B chunk

  auto stageA = [&](int buf, int h, int k0){
    const u16* s = A + (size_t)(m0 + h*128 + wave*16 + srow) * G1_K + k0 + scol;
    u16* d = ldsA + (buf*2 + h)*8192 + wave*1024;
    gl_lds16(s,                  d);        // rows wave*16 .. +7
    gl_lds16(s + (size_t)8*G1_K, d + 512);  // rows +8 .. +15
  };
  auto stageB = [&](int buf, int h, int k0){
    const u16* s = Bt + (size_t)(n0 + h*128 + wave*16 + srow) * G1_K + k0 + scol;
    u16* d = ldsB + (buf*2 + h)*8192 + wave*1024;
    gl_lds16(s,                  d);
    gl_lds16(s + (size_t)8*G1_K, d + 512);
  };

  f32x4 acc[8][4];
  #pragma unroll
  for (int i = 0; i < 8; ++i)
    #pragma unroll
    for (int j = 0; j < 4; ++j) acc[i][j] = (f32x4){0.f,0.f,0.f,0.f};

  s16x8 aA[2][2], aB[2][2];       // alternating A-quadrant frags
  s16x8 bX[4][2], bY[4][2];       // alternating per-tile B frags

  #define READ_AQ(dst, Q, nb)                                            \
    { const u16* p_ = ldsA + ((nb)*2 + wr)*8192 + (Q)*2048 + arow;       \
      dst[0][0] = *(const s16x8*)(p_ + cx0);                             \
      dst[0][1] = *(const s16x8*)(p_ + cx1);                             \
      dst[1][0] = *(const s16x8*)(p_ + 1024 + cx0);                      \
      dst[1][1] = *(const s16x8*)(p_ + 1024 + cx1); }
  #define READ_B8(dst, nb)                                               \
    { const u16* p_ = ldsB + ((nb)*2 + (wc>>1))*8192 + (wc&1)*4096 + arow; \
      _Pragma("unroll")                                                  \
      for (int nj_ = 0; nj_ < 4; ++nj_){                                 \
        dst[nj_][0] = *(const s16x8*)(p_ + nj_*1024 + cx0);              \
        dst[nj_][1] = *(const s16x8*)(p_ + nj_*1024 + cx1); } }
  #define MFMA_Q(Q, AF, BF)                                              \
    { _Pragma("unroll")                                                  \
      for (int nj_ = 0; nj_ < 4; ++nj_){                                 \
        _Pragma("unroll")                                                \
        for (int kk_ = 0; kk_ < 2; ++kk_){                               \
          acc[2*(Q)][nj_]   = __builtin_amdgcn_mfma_f32_16x16x32_bf16(AF[0][kk_], BF[nj_][kk_], acc[2*(Q)][nj_],   0,0,0); \
          acc[2*(Q)+1][nj_] = __builtin_amdgcn_mfma_f32_16x16x32_bf16(AF[1][kk_], BF[nj_][kk_], acc[2*(Q)+1][nj_], 0,0,0); } } }

  // ---- prologue: stage B(0),A(0),B(1),A(1) in that issue order; drain tile0; reads ----
  stageB(0,0,0); stageB(0,1,0); stageA(0,0,0); stageA(0,1,0);
  stageB(1,0,64); stageB(1,1,64); stageA(1,0,64); stageA(1,1,64);
  asm volatile("s_waitcnt vmcnt(8)" ::: "memory");   // own B(0)+A(0) done; tile1 in flight
  __builtin_amdgcn_s_barrier();                      // all waves' tile0 DMAs visible
  __builtin_amdgcn_sched_barrier(0);
  READ_B8(bX, 0);
  READ_AQ(aA, 0, 0);

  auto tile_body = [&](int tt, int buf, s16x8 (&bC)[4][2], s16x8 (&bN)[4][2]){
    const int k2 = (tt+2 < G1_NT ? tt+2 : G1_NT-1) * 64;   // clamped: junk restage, never read
    const int nb = buf ^ 1;

    // ---- p0: read Q1 -> aB; MFMA Q0 ----
    READ_AQ(aB, 1, buf);
    __builtin_amdgcn_s_barrier();
    asm volatile("s_waitcnt lgkmcnt(4)" ::: "memory");   // drains p3's 12; Q1 stays out
    __builtin_amdgcn_sched_barrier(0);
    __builtin_amdgcn_s_setprio(1);
    MFMA_Q(0, aA, bC);
    __builtin_amdgcn_s_setprio(0);
    __builtin_amdgcn_s_barrier();

    // ---- p1: read Q2 -> aA; stage B0(t+2) over B(t) (B(t) reads drained at p0 lgkm) ----
    READ_AQ(aA, 2, buf);
    stageB(buf, 0, k2);
    __builtin_amdgcn_s_barrier();
    asm volatile("s_waitcnt lgkmcnt(4)" ::: "memory");   // drains Q1; Q2 stays out
    __builtin_amdgcn_sched_barrier(0);
    __builtin_amdgcn_s_setprio(1);
    MFMA_Q(1, aB, bC);
    __builtin_amdgcn_s_setprio(0);
    __builtin_amdgcn_s_barrier();

    // ---- p2: read Q3 -> aB; stage B1(t+2) ----
    READ_AQ(aB, 3, buf);
    stageB(buf, 1, k2);
    __builtin_amdgcn_s_barrier();
    asm volatile("s_waitcnt lgkmcnt(4)" ::: "memory");   // drains Q2; Q3 stays out
    __builtin_amdgcn_sched_barrier(0);
    __builtin_amdgcn_s_setprio(1);
    MFMA_Q(2, aA, bC);
    __builtin_amdgcn_s_setprio(0);
    __builtin_amdgcn_s_barrier();

    // ---- p3: publish t+1; reads of t+1; drain own A(t)-reads; barrier; stage A(t+2);
    //          MFMA Q3 ----
    asm volatile("s_waitcnt vmcnt(4)" ::: "memory");   // drains B(t+1)+A(t+1); B(t+2) out
    __builtin_amdgcn_s_barrier();                      // all waves' t+1 DMAs visible
    __builtin_amdgcn_sched_barrier(0);
    READ_B8(bN, nb);
    READ_AQ(aA, 0, nb);
    asm volatile("s_waitcnt lgkmcnt(12)" ::: "memory"); // drains Q3 (all own A(t) reads done)
    __builtin_amdgcn_sched_barrier(0);
    __builtin_amdgcn_s_barrier();                      // ALL waves' A(t) reads done -> WAR-safe
    stageA(buf, 0, k2);                                // A(t+2) over A(t); 4 phases ahead
    stageA(buf, 1, k2);
    __builtin_amdgcn_s_setprio(1);
    MFMA_Q(3, aB, bC);
    __builtin_amdgcn_s_setprio(0);
    __builtin_amdgcn_s_barrier();
  };

  for (int tt2 = 0; tt2 < G1_NT; tt2 += 2) {
    tile_body(tt2,     0, bX, bY);
    tile_body(tt2 + 1, 1, bY, bX);
  }

  // ---- epilogue: drain junk DMA, restage C through LDS (pad 264), coalesced stores ----
  asm volatile("s_waitcnt vmcnt(0)" ::: "memory");
  __syncthreads();

  #pragma unroll
  for (int nj = 0; nj < 4; ++nj) {
    const int colg = n0 + wc*64 + nj*16 + lrow;
    const float bv = bias[colg];
    const int coll = wc*64 + nj*16 + lrow;
    #pragma unroll
    for (int mi = 0; mi < 8; ++mi) {
      #pragma unroll
      for (int r = 0; r < 4; ++r) {
        const int rowl = wr*128 + mi*16 + q*4 + r;   // C/D: col=lane&15, row=quad*4+reg
        ldsAll[rowl*264 + coll] = f2b(silu_f(acc[mi][nj][r] + bv));
      }
    }
  }
  __syncthreads();

  u16* op = (n0 < D_INNER) ? out0 : out1;
  const int colbase = n0 & (D_INNER - 1);
  #pragma unroll
  for (int it = 0; it < 16; ++it) {
    const int f   = it*512 + tid;
    const int row = f >> 5;           // 0..255
    const int ch  = f & 31;           // 16B chunk within 512B row-span
    u16x8 v = *(const u16x8*)(ldsAll + row*264 + ch*8);
    *(u16x8*)(op + (size_t)(m0 + row)*D_INNER + colbase + ch*8) = v;
  }
  #undef READ_AQ
  #undef READ_B8
  #undef MFMA_Q
}

// ------------- MFMA GEMM, double-buffered DMA, 1 barrier/iter (kept for gemm2) -------------
// MODE 0: outf[row*N+col] = f32(acc + bias[col])          (final output, f32)
template<int MODE>
__global__ __launch_bounds__(256) void gemm_bt(const u16* __restrict__ A,
                                               const u16* __restrict__ Bt,
                                               const float* __restrict__ bias,
                                               u16* __restrict__ out0,
                                               u16* __restrict__ out1,
                                               float* __restrict__ outf,
                                               int M, int N, int K, int n_per_xcd){
  __shared__ __align__(16) u16 Asb[2][128*32];   // unpadded: DMA layout constraint
  __shared__ __align__(16) u16 Bsb[2][128*32];
  const int bid = blockIdx.x;
  const int xcd = bid & 7, t2 = bid >> 3;
  const int n0 = (xcd * n_per_xcd + (t2 % n_per_xcd)) * 128;
  const int m0 = (t2 / n_per_xcd) * 128;
  const int t    = threadIdx.x;
  const int wave = t >> 6, lane = t & 63;
  const int wm   = (wave >> 1) * 64, wn = (wave & 1) * 64;
  const int lrow = lane & 15, kq = (lane >> 4) * 8;
  const int srow = lane >> 2;            // staging: row within 16-row block
  const int scol = (lane & 3) * 8;       // staging: 8-u16 chunk within row

  f32x4 acc[4][4];
  #pragma unroll
  for (int i = 0; i < 4; ++i)
    #pragma unroll
    for (int j = 0; j < 4; ++j)
      acc[i][j] = (f32x4){0.f, 0.f, 0.f, 0.f};

  auto stage = [&](int buf, int k0){
    #pragma unroll
    for (int i = 0; i < 2; ++i) {
      int R0 = (wave*2 + i) * 16;        // 0,16,...,112
      gl_lds16(&A [(size_t)(m0 + R0 + srow)*K + k0 + scol], &Asb[buf][R0*32]);
      gl_lds16(&Bt[(size_t)(n0 + R0 + srow)*K + k0 + scol], &Bsb[buf][R0*32]);
    }
  };

  const int KT = K >> 5;
  stage(0, 0);
  __syncthreads();
  for (int kt = 0; kt < KT; ++kt) {
    const int cur = kt & 1;
    if (kt + 1 < KT) stage(1 - cur, (kt + 1) * 32);   // prefetch overlaps compute below
    s16x8 af[4], bfr[4];
    #pragma unroll
    for (int i = 0; i < 4; ++i) af[i]  = *(const s16x8*)&Asb[cur][(wm + i*16 + lrow)*32 + kq];
    #pragma unroll
    for (int j = 0; j < 4; ++j) bfr[j] = *(const s16x8*)&Bsb[cur][(wn + j*16 + lrow)*32 + kq];
    #pragma unroll
    for (int i = 0; i < 4; ++i)
      #pragma unroll
      for (int j = 0; j < 4; ++j)
        acc[i][j] = __builtin_amdgcn_mfma_f32_16x16x32_bf16(af[i], bfr[j], acc[i][j], 0, 0, 0);
    __syncthreads();   // drains prefetch DMA + protects cur buffer reuse
  }

  const int Nh = N >> 1;
  #pragma unroll
  for (int i = 0; i < 4; ++i) {
    #pragma unroll
    for (int j = 0; j < 4; ++j) {
      int col = n0 + wn + j*16 + lrow;
      float bv = bias[col];
      #pragma unroll
      for (int r = 0; r < 4; ++r) {
        int row = m0 + wm + i*16 + (lane >> 4)*4 + r;   // C/D: col=lane&15, row=quad*4+reg
        float v = acc[i][j][r] + bv;
        if (MODE == 0) {
          outf[(size_t)row * N + col] = v;
        } else {
          float s = silu_f(v);
          if (col < Nh) out0[(size_t)row * Nh + col]        = f2b(s);
          else          out1[(size_t)row * Nh + (col - Nh)] = f2b(s);
        }
      }
    }
  }
}

// ------------- B/C projection GEMM with FUSED depthwise conv(3) -------------
__global__ __launch_bounds__(256) void bc_gemm_k(const u16* __restrict__ xs,
                                                 const float* __restrict__ conv_w,
                                                 const float* __restrict__ conv_b,
                                                 const u16* __restrict__ Wt,
                                                 float* __restrict__ partial){
  __shared__ __align__(16) u16 Rsb[130*40];   // raw rows m0-1 .. m0+128
  __shared__ __align__(16) u16 Asb[128*40];   // conv output tile
  __shared__ __align__(16) u16 Wsb[32*40];
  const int kseg = blockIdx.x;
  const int m0   = blockIdx.y * 128;
  const int t    = threadIdx.x;
  const int wave = t >> 6, lane = t & 63;
  const int wm   = wave * 32;
  const int lrow = lane & 15, kq = (lane >> 4) * 8;
  const bool zfirst = (m0 & (SEQ-1)) == 0;          // raw row 0   -> zero (seq start)
  const bool zlast  = ((m0+128) & (SEQ-1)) == 0;    // raw row 129 -> zero (seq end)
  const int ccol = t & 31, r0c = (t >> 5) * 16;     // conv thread mapping

  f32x4 acc[2][2];
  #pragma unroll
  for (int i = 0; i < 2; ++i)
    #pragma unroll
    for (int j = 0; j < 2; ++j)
      acc[i][j] = (f32x4){0.f, 0.f, 0.f, 0.f};

  const int kbase = kseg * (D_INNER / KSEG);
  for (int ks = 0; ks < (D_INNER / KSEG); ks += 32) {
    int k0 = kbase + ks;
    if (t < 128) {
      int f = t * 8;
      int r = f >> 5, c = f & 31;
      *(u16x8*)&Wsb[r*40 + c] = *(const u16x8*)&Wt[(size_t)r*D_INNER + k0 + c];
    }
    #pragma unroll
    for (int i = 0; i < 3; ++i) {
      int idx = i*256 + t;
      if (idx < 520) {
        int r = idx >> 2, c = (idx & 3) * 8;
        u16x8 v = (u16x8){0,0,0,0,0,0,0,0};
        bool zero = (r == 0 && zfirst) || (r == 129 && zlast);
        if (!zero)
          v = *(const u16x8*)&xs[(size_t)(m0 - 1 + r)*D_INNER + k0 + c];
        *(u16x8*)&Rsb[r*40 + c] = v;
      }
    }
    __syncthreads();
    {
      const int dcol = k0 + ccol;
      const float cw0 = conv_w[dcol*3], cw1 = conv_w[dcol*3+1], cw2 = conv_w[dcol*3+2];
      const float cbv = conv_b[dcol];
      #pragma unroll
      for (int r = 0; r < 16; ++r) {
        int rr = r0c + r;
        float v = cw0 * b2f(Rsb[rr*40 + ccol])
                + cw1 * b2f(Rsb[(rr+1)*40 + ccol])
                + cw2 * b2f(Rsb[(rr+2)*40 + ccol]) + cbv;
        Asb[rr*40 + ccol] = f2b(v);
      }
    }
    __syncthreads();
    s16x8 af[2], wf[2];
    #pragma unroll
    for (int i = 0; i < 2; ++i) af[i] = *(const s16x8*)&Asb[(wm + i*16 + lrow)*40 + kq];
    #pragma unroll
    for (int j = 0; j < 2; ++j) wf[j] = *(const s16x8*)&Wsb[(j*16 + lrow)*40 + kq];
    #pragma unroll
    for (int i = 0; i < 2; ++i)
      #pragma unroll
      for (int j = 0; j < 2; ++j)
        acc[i][j] = __builtin_amdgcn_mfma_f32_16x16x32_bf16(af[i], wf[j], acc[i][j], 0, 0, 0);
    __syncthreads();
  }

  #pragma unroll
  for (int i = 0; i < 2; ++i)
    #pragma unroll
    for (int j = 0; j < 2; ++j)
      #pragma unroll
      for (int r = 0; r < 4; ++r) {
        int row = m0 + wm + i*16 + (lane >> 4)*4 + r;
        int col = j*16 + lrow;
        partial[((size_t)kseg * ML + row) * 32 + col] = acc[i][j][r];
      }
}

// ------------- reduce partials + bias + mod -> Bbuf/Cbuf -------------
__global__ __launch_bounds__(256) void bc_reduce_k(const float* __restrict__ partial,
    const float* __restrict__ b_B, const float* __restrict__ B_mod,
    const float* __restrict__ b_C, const float* __restrict__ C_mod,
    float* __restrict__ Bbuf, float* __restrict__ Cbuf){
  int g = blockIdx.x * 256 + threadIdx.x;   // < ML*32
  int row = g >> 5, col = g & 31;
  int b = row >> 11;
  float s = 0.f;
  #pragma unroll
  for (int seg = 0; seg < KSEG; ++seg)
    s += partial[(size_t)seg * ML * 32 + g];
  if (col < 16) Bbuf[(size_t)row*16 + col]      = s + b_B[col]      + B_mod[b*16 + col];
  else          Cbuf[(size_t)row*16 + col - 16] = s + b_C[col - 16] + C_mod[b*16 + col - 16];
}

// ------------- chunked scan, pass 1 (fused conv): local chunk-final states -------------
__global__ __launch_bounds__(256) void state_k(const u16* __restrict__ xs,
    const float* __restrict__ conv_w, const float* __restrict__ conv_b,
    const float* __restrict__ Bbuf, const float* __restrict__ A_log,
    float* __restrict__ hend){
  int c = blockIdx.x, db = blockIdx.y, b = blockIdx.z;
  int d = db*256 + threadIdx.x;

  float Abar[16];
  #pragma unroll
  for (int s = 0; s < 16; ++s)
    Abar[s] = __expf(-0.1f * __expf(A_log[d*16 + s]));
  float h[16];
  #pragma unroll
  for (int s = 0; s < 16; ++s) h[s] = 0.f;

  const float w0 = conv_w[d*3], w1 = conv_w[d*3+1], w2 = conv_w[d*3+2], cb = conv_b[d];
  size_t base = (size_t)b * SEQ * D_INNER + (size_t)c * CH * D_INNER + d;
  const float* Br = Bbuf + ((size_t)b * SEQ + (size_t)c * CH) * 16;
  const int l0 = c * CH;

  float xm = (l0 > 0) ? b2f(xs[base - D_INNER]) : 0.f;
  float x0 = b2f(xs[base]);
  float xp = b2f(xs[base + D_INNER]);
  float Bc[16];
  #pragma unroll
  for (int s = 0; s < 16; ++s) Bc[s] = Br[s];

  for (int l = 0; l < CH; ++l){
    float xq = 0.f;
    if (l0 + l + 2 < SEQ) xq = b2f(xs[base + (size_t)(l+2)*D_INNER]);
    float Bl[16];
    #pragma unroll
    for (int s = 0; s < 16; ++s) Bl[s] = Bc[s];
    if (l < CH-1){
      #pragma unroll
      for (int s = 0; s < 16; ++s) Bc[s] = Br[(l+1)*16 + s];
    }
    float xc = w0*xm + w1*x0 + w2*xp + cb;
    #pragma unroll
    for (int s = 0; s < 16; ++s)
      h[s] = Abar[s]*h[s] + xc*Bl[s];
    xm = x0; x0 = xp; xp = xq;
  }
  float* hp = hend + (((size_t)(b*NCHUNK + c))*D_INNER + d)*16;
  #pragma unroll
  for (int q = 0; q < 4; ++q)
    *(f32x4*)(hp + q*4) = (f32x4){h[q*4], h[q*4+1], h[q*4+2], h[q*4+3]};
}

// ------------- chunked scan, pass 2: prefix across chunks -------------
__global__ __launch_bounds__(256) void prefix_k(const float* __restrict__ hend,
    const float* __restrict__ A_log, float* __restrict__ hin){
  int g = blockIdx.x*256 + threadIdx.x;
  int s = g & 15;
  int d = (g >> 4) & (D_INNER-1);
  int b = g >> 15;
  float decay = __expf(-0.1f * (float)CH * __expf(A_log[d*16 + s]));
  size_t stride = (size_t)D_INNER * 16;
  const float* he = hend + (size_t)b*NCHUNK*stride + (size_t)d*16 + s;
  float*       hi = hin  + (size_t)b*NCHUNK*stride + (size_t)d*16 + s;
  float h = 0.f;
  for (int c0 = 0; c0 < NCHUNK; c0 += 8){
    float v[8];
    #pragma unroll
    for (int i = 0; i < 8; ++i) v[i] = he[(size_t)(c0+i)*stride];
    #pragma unroll
    for (int i = 0; i < 8; ++i){
      hi[(size_t)(c0+i)*stride] = h;
      h = decay*h + v[i];
    }
  }
}

// ------------- chunked scan, pass 3 (fused conv): full scan per chunk from hin -------------
// ybuf MUST NOT alias xs: xs rows l+1/l+2 are read across chunk boundaries by other blocks.
__global__ __launch_bounds__(256) void scan2_k(const u16* __restrict__ xs,
    const u16* __restrict__ gate,
    const float* __restrict__ conv_w, const float* __restrict__ conv_b,
    const float* __restrict__ Bbuf, const float* __restrict__ Cbuf,
    const float* __restrict__ A_log, const float* __restrict__ Dp,
    const float* __restrict__ hin, u16* __restrict__ ybuf){
  int c = blockIdx.x, db = blockIdx.y, b = blockIdx.z;
  int d = db*256 + threadIdx.x;

  float Abar[16];
  #pragma unroll
  for (int s = 0; s < 16; ++s)
    Abar[s] = __expf(-0.1f * __expf(A_log[d*16 + s]));
  float h[16];
  const float* hp = hin + (((size_t)(b*NCHUNK + c))*D_INNER + d)*16;
  #pragma unroll
  for (int q = 0; q < 4; ++q){
    f32x4 v = *(const f32x4*)(hp + q*4);
    #pragma unroll
    for (int j = 0; j < 4; ++j) h[q*4 + j] = v[j];
  }
  float Dd = Dp[d];
  const float w0 = conv_w[d*3], w1 = conv_w[d*3+1], w2 = conv_w[d*3+2], cb = conv_b[d];

  size_t base = (size_t)b * SEQ * D_INNER + (size_t)c * CH * D_INNER + d;
  const float* Br = Bbuf + ((size_t)b * SEQ + (size_t)c * CH) * 16;
  const float* Cr = Cbuf + ((size_t)b * SEQ + (size_t)c * CH) * 16;
  const int l0 = c * CH;

  float xm = (l0 > 0) ? b2f(xs[base - D_INNER]) : 0.f;
  float x0 = b2f(xs[base]);
  float xp = b2f(xs[base + D_INNER]);
  float Bc[16], Cc[16];
  #pragma unroll
  for (int s = 0; s < 16; ++s){ Bc[s] = Br[s]; Cc[s] = Cr[s]; }
  float gcur = b2f(gate[base]);

  for (int l = 0; l < CH; ++l){
    float xq = 0.f;
    if (l0 + l + 2 < SEQ) xq = b2f(xs[base + (size_t)(l+2)*D_INNER]);
    float gnext = (l < CH-1) ? b2f(gate[base + (size_t)(l+1)*D_INNER]) : 0.f;
    float Bl[16], Cl[16];
    #pragma unroll
    for (int s = 0; s < 16; ++s){ Bl[s] = Bc[s]; Cl[s] = Cc[s]; }
    if (l < CH-1){
      #pragma unroll
      for (int s = 0; s < 16; ++s){ Bc[s] = Br[(l+1)*16 + s]; Cc[s] = Cr[(l+1)*16 + s]; }
    }
    float xc = w0*xm + w1*x0 + w2*xp + cb;
    float ya[4] = {0.f, 0.f, 0.f, 0.f};
    #pragma unroll
    for (int s = 0; s < 16; ++s){
      float hv = Abar[s]*h[s] + xc*Bl[s];
      h[s] = hv;
      ya[s & 3] += hv * Cl[s];
    }
    float y = ((ya[0]+ya[1]) + (ya[2]+ya[3]) + Dd*xc) * gcur;
    ybuf[base + (size_t)l*D_INNER] = f2b(y);
    xm = x0; x0 = xp; xp = xq; gcur = gnext;
  }
}

extern "C" void kernel_launch(void* const* d_in, const int* in_sizes, int n_in,
                              void* d_out, int out_size, void* d_ws, size_t ws_size,
                              hipStream_t stream){
  const float* x      = (const float*)d_in[0];
  const float* B_mod  = (const float*)d_in[1];
  const float* C_mod  = (const float*)d_in[2];
  const float* W_in   = (const float*)d_in[3];
  const float* b_in   = (const float*)d_in[4];
  const float* conv_w = (const float*)d_in[5];
  const float* conv_b = (const float*)d_in[6];
  const float* A_log  = (const float*)d_in[7];
  const float* Dp     = (const float*)d_in[8];
  const float* W_B    = (const float*)d_in[9];
  const float* b_B    = (const float*)d_in[10];
  const float* W_C    = (const float*)d_in[11];
  const float* b_C    = (const float*)d_in[12];
  const float* W_out  = (const float*)d_in[13];
  const float* b_out  = (const float*)d_in[14];
  float* out = (float*)d_out;   // reference output dtype is float32

  char* ws = (char*)d_ws;
  size_t off = 0;
  auto alloc = [&](size_t bytes)->char* {
    char* p = ws + off; off += (bytes + 255) & ~(size_t)255; return p;
  };
  u16* Wt_in  = (u16*)alloc((size_t)(2*D_INNER)*D_MODEL*2); // 8.39 MB; dead after gemm1
  u16* Wt_out = (u16*)alloc((size_t)D_MODEL*D_INNER*2);     // 4.2 MB
  u16* xs     = (u16*)alloc((size_t)ML*D_INNER*2);          // silu(x_ssm), conv fused downstream
  u16* gatep  = (u16*)alloc((size_t)ML*D_INNER*2);          // silu(x_res)
  u16* ybuf   = (u16*)alloc((size_t)ML*D_INNER*2);          // scan output
  float* Bbuf = (float*)alloc((size_t)ML*D_STATE*4);
  float* Cbuf = (float*)alloc((size_t)ML*D_STATE*4);
  u16* xbf    = (u16*)alloc((size_t)ML*D_MODEL*2);          // 16.8 MB; dead after gemm1
  float* hin  = (float*)alloc((size_t)BATCH*NCHUNK*D_INNER*16*4);
  u16* Wt_bc  = (u16*)alloc((size_t)32*D_INNER*2);          // 131 KB
  float* hend    = (float*)xbf;    // reuse: xbf dead before state_k
  float* partial = (float*)Wt_in;  // reuse: Wt_in dead after gemm1 (8.39 MB, exact)

  // fused prep: W_in^T, W_out^T, cast(x), Wt_bc (was 4 launches)
  prep_k<<<dim3(10496), 256, 0, stream>>>(W_in, W_out, x, W_B, W_C,
                                          Wt_in, Wt_out, xbf, Wt_bc);

  // gemm1: deep-A-prefetch 4-phase 256x256; 512 blocks x 512 threads; 2 n-blocks per XCD
  gemm1_k<<<dim3(512), 512, 0, stream>>>(xbf, Wt_in, b_in, xs, gatep);

  // conv(3) fused into bc_gemm/state/scan2 — no conv pass, no xconv tensor
  bc_gemm_k<<<dim3(KSEG, ML/128), 256, 0, stream>>>(xs, conv_w, conv_b, Wt_bc, partial);
  bc_reduce_k<<<dim3((ML*32)/256), 256, 0, stream>>>(
      partial, b_B, B_mod, b_C, C_mod, Bbuf, Cbuf);

  state_k<<<dim3(NCHUNK, D_INNER/256, BATCH), 256, 0, stream>>>(
      xs, conv_w, conv_b, Bbuf, A_log, hend);
  prefix_k<<<dim3((BATCH*D_INNER*16)/256), 256, 0, stream>>>(hend, A_log, hin);
  scan2_k<<<dim3(NCHUNK, D_INNER/256, BATCH), 256, 0, stream>>>(
      xs, gatep, conv_w, conv_b, Bbuf, Cbuf, A_log, Dp, hin, ybuf);

  // gemm2: N-blocks=8 -> 1 per XCD; 512 blocks total
  gemm_bt<0><<<dim3(512), 256, 0, stream>>>(
      ybuf, Wt_out, b_out, nullptr, nullptr, out, ML, D_MODEL, D_INNER, 1);
}

// Round 9
// 370.780 us; speedup vs baseline: 1.1481x; 1.1481x over previous
//
#include <hip/hip_runtime.h>
#include <stdint.h>

#define D_MODEL 1024
#define D_STATE 16
#define D_INNER 2048
#define BATCH   4
#define SEQ     2048
#define ML      (BATCH*SEQ)   // 8192 rows
#define CH      64
#define NCHUNK  (SEQ/CH)      // 32
#define KSEG    8             // K-split for B/C projection GEMM

typedef unsigned short u16;
typedef u16   u16x8  __attribute__((ext_vector_type(8)));
typedef short s16x8  __attribute__((ext_vector_type(8)));
typedef float f32x4  __attribute__((ext_vector_type(4)));

__device__ __forceinline__ float b2f(u16 u){
  union { uint32_t i; float f; } v; v.i = ((uint32_t)u) << 16; return v.f;
}
__device__ __forceinline__ u16 f2b(float f){
  uint32_t x = __float_as_uint(f);
  return (u16)((x + 0x7fffu + ((x >> 16) & 1u)) >> 16);   // RNE
}
__device__ __forceinline__ float silu_f(float v){
  return v / (1.f + __expf(-v));
}
// async global->LDS, 16 B per lane; lds base must be wave-uniform (lane i lands at base + i*16)
__device__ __forceinline__ void gl_lds16(const void* gp, void* lp){
  __builtin_amdgcn_global_load_lds(
      (const __attribute__((address_space(1))) void*)gp,
      (__attribute__((address_space(3))) void*)lp, 16, 0, 0);
}

// ------------- fused prep: W_in^T, W_out^T, cast(x), Wt_bc — one launch -------------
// blocks [0,4096): W_in transpose (R=1024,C=4096); [4096,6144): W_out transpose
// (R=2048,C=1024); [6144,10240): cast x; [10240,10496): bc_wt.
__global__ __launch_bounds__(256) void prep_k(const float* __restrict__ W_in,
                                              const float* __restrict__ W_out,
                                              const float* __restrict__ x,
                                              const float* __restrict__ W_B,
                                              const float* __restrict__ W_C,
                                              u16* __restrict__ Wt_in,
                                              u16* __restrict__ Wt_out,
                                              u16* __restrict__ xbf,
                                              u16* __restrict__ Wt_bc){
  __shared__ float tile[32][33];
  int bb = blockIdx.x;
  if (bb < 6144) {
    const float* in; u16* out; int R, C, bx, by;
    if (bb < 4096) { in = W_in;  out = Wt_in;  R = 1024; C = 4096;
                     bx = (bb & 127) * 32; by = (bb >> 7) * 32; }
    else { bb -= 4096; in = W_out; out = Wt_out; R = 2048; C = 1024;
                     bx = (bb & 31) * 32; by = (bb >> 5) * 32; }
    int tx = threadIdx.x & 31, ty = threadIdx.x >> 5;
    #pragma unroll
    for (int i = 0; i < 32; i += 8)
      tile[ty + i][tx] = in[(size_t)(by + ty + i) * C + bx + tx];
    __syncthreads();
    #pragma unroll
    for (int i = 0; i < 32; i += 8)
      out[(size_t)(bx + ty + i) * R + by + tx] = f2b(tile[tx][ty + i]);
  } else if (bb < 10240) {
    bb -= 6144;
    size_t i = ((size_t)bb * 256 + threadIdx.x) * 8;
    f32x4 a = *(const f32x4*)(x + i);
    f32x4 b = *(const f32x4*)(x + i + 4);
    u16x8 o;
    #pragma unroll
    for (int j = 0; j < 4; ++j){ o[j] = f2b(a[j]); o[4+j] = f2b(b[j]); }
    *(u16x8*)(xbf + i) = o;
  } else {
    bb -= 10240;
    int n = bb >> 3;                         // 0..31
    int k = (bb & 7) * 256 + threadIdx.x;    // 0..2047
    const float* src = (n < 16) ? W_B : W_C;
    Wt_bc[(size_t)n * D_INNER + k] = f2b(src[(size_t)k * 16 + (n & 15)]);
  }
}

// ================= 4-phase 256x256 GEMM for in_proj (full-line staging) =================
// R7 schedule restored (best measured: 86us @ MfmaUtil 33 on a fast container).
// R8's deep-A-prefetch was neutral-to-negative (extra p3 barrier ate the prefetch gain).
// Full-line staging (8 rows x 128B per gl_lds16) with involutive chunk-XOR; conflicts=0.
// RACE RULES (R1): vmcnt drains only OWN DMAs -> cross-wave LDS reads sit after
// {all waves drained + s_barrier}; every stage-over-slot separated from all waves'
// last-read drain point by a barrier.
#define G1_K  1024
#define G1_NT (G1_K/64)   // 16 K-tiles

__global__ __launch_bounds__(512, 2) void gemm1_k(const u16* __restrict__ A,
                                                  const u16* __restrict__ Bt,
                                                  const float* __restrict__ bias,
                                                  u16* __restrict__ out0,
                                                  u16* __restrict__ out1){
  __shared__ __align__(16) u16 ldsAll[256*264];  // 135168 B; staging uses first 128 KB,
  u16* ldsA = ldsAll;                            // epilogue reuses full array (pad 264)
  u16* ldsB = ldsAll + 4*8192;

  const int bid = blockIdx.x;
  const int xcd = bid & 7, t2 = bid >> 3;
  const int n0 = (xcd*2 + (t2 & 1)) * 256;     // 16 n-blocks, 2 per XCD
  const int m0 = (t2 >> 1) * 256;              // 32 m-blocks

  const int tid  = threadIdx.x;
  const int wave = tid >> 6, lane = tid & 63;
  const int wr = wave >> 2;                    // 0..1: M half
  const int wc = wave & 3;                     // 0..3: N quarter
  const int lrow = lane & 15;
  const int q    = lane >> 4;                  // 0..3

  // per-lane swizzled read cols (u16): kk=0 and kk=1; (c^4)*8 == c*8 ^ 32
  const int cx0  = ((q ^ (lrow & 7)) << 3);
  const int cx1  = cx0 ^ 32;
  const int arow = lrow * 64;

  // staging: one gl_lds16 = 8 rows x 128B (full lines), source col pre-swizzled
  const int srow = lane >> 3;                          // 0..7
  const int scol = (((lane & 7) ^ (lane >> 3)) << 3);  // swizzled 16B chunk

  auto stageA = [&](int buf, int h, int k0){
    const u16* s = A + (size_t)(m0 + h*128 + wave*16 + srow) * G1_K + k0 + scol;
    u16* d = ldsA + (buf*2 + h)*8192 + wave*1024;
    gl_lds16(s,                  d);        // rows wave*16 .. +7
    gl_lds16(s + (size_t)8*G1_K, d + 512);  // rows +8 .. +15
  };
  auto stageB = [&](int buf, int h, int k0){
    const u16* s = Bt + (size_t)(n0 + h*128 + wave*16 + srow) * G1_K + k0 + scol;
    u16* d = ldsB + (buf*2 + h)*8192 + wave*1024;
    gl_lds16(s,                  d);
    gl_lds16(s + (size_t)8*G1_K, d + 512);
  };

  f32x4 acc[8][4];
  #pragma unroll
  for (int i = 0; i < 8; ++i)
    #pragma unroll
    for (int j = 0; j < 4; ++j) acc[i][j] = (f32x4){0.f,0.f,0.f,0.f};

  s16x8 aA[2][2], aB[2][2];       // alternating A-quadrant frags
  s16x8 bX[4][2], bY[4][2];       // alternating per-tile B frags

  #define READ_AQ(dst, Q, nb)                                            \
    { const u16* p_ = ldsA + ((nb)*2 + wr)*8192 + (Q)*2048 + arow;       \
      dst[0][0] = *(const s16x8*)(p_ + cx0);                             \
      dst[0][1] = *(const s16x8*)(p_ + cx1);                             \
      dst[1][0] = *(const s16x8*)(p_ + 1024 + cx0);                      \
      dst[1][1] = *(const s16x8*)(p_ + 1024 + cx1); }
  #define READ_B8(dst, nb)                                               \
    { const u16* p_ = ldsB + ((nb)*2 + (wc>>1))*8192 + (wc&1)*4096 + arow; \
      _Pragma("unroll")                                                  \
      for (int nj_ = 0; nj_ < 4; ++nj_){                                 \
        dst[nj_][0] = *(const s16x8*)(p_ + nj_*1024 + cx0);              \
        dst[nj_][1] = *(const s16x8*)(p_ + nj_*1024 + cx1); } }
  #define MFMA_Q(Q, AF, BF)                                              \
    { _Pragma("unroll")                                                  \
      for (int nj_ = 0; nj_ < 4; ++nj_){                                 \
        _Pragma("unroll")                                                \
        for (int kk_ = 0; kk_ < 2; ++kk_){                               \
          acc[2*(Q)][nj_]   = __builtin_amdgcn_mfma_f32_16x16x32_bf16(AF[0][kk_], BF[nj_][kk_], acc[2*(Q)][nj_],   0,0,0); \
          acc[2*(Q)+1][nj_] = __builtin_amdgcn_mfma_f32_16x16x32_bf16(AF[1][kk_], BF[nj_][kk_], acc[2*(Q)+1][nj_], 0,0,0); } } }

  // ---- prologue: stage tile0 + B(t1); drain tile0; BARRIER; then cross-wave reads ----
  stageA(0,0,0); stageA(0,1,0); stageB(0,0,0); stageB(0,1,0);
  stageB(1,0,64); stageB(1,1,64);
  asm volatile("s_waitcnt vmcnt(4)" ::: "memory");   // own tile0 DMAs done; B(t1) in flight
  __builtin_amdgcn_s_barrier();                       // ALL waves' tile0 DMAs visible
  __builtin_amdgcn_sched_barrier(0);                  // pin reads below the barrier
  READ_B8(bX, 0);
  READ_AQ(aA, 0, 0);

  auto tile_body = [&](int tt, int buf, s16x8 (&bC)[4][2], s16x8 (&bN)[4][2]){
    const int k1 = (tt+1 < G1_NT ? tt+1 : G1_NT-1) * 64;   // clamped: junk restage, never read
    const int k2 = (tt+2 < G1_NT ? tt+2 : G1_NT-1) * 64;
    const int nb = buf ^ 1;

    // ---- p0: read Q1 -> aB; stage A(t+1); MFMA Q0 ----
    READ_AQ(aB, 1, buf);
    stageA(nb, 1, k1);
    stageA(nb, 0, k1);
    __builtin_amdgcn_s_barrier();
    asm volatile("s_waitcnt lgkmcnt(4)" ::: "memory");   // drains p3's 12; Q1 stays out
    __builtin_amdgcn_sched_barrier(0);
    __builtin_amdgcn_s_setprio(1);
    MFMA_Q(0, aA, bC);
    __builtin_amdgcn_s_setprio(0);
    __builtin_amdgcn_s_barrier();

    // ---- p1: read Q2 -> aA; stage B0(t+2); MFMA Q1 ----
    READ_AQ(aA, 2, buf);
    stageB(buf, 0, k2);
    __builtin_amdgcn_s_barrier();
    asm volatile("s_waitcnt lgkmcnt(4)" ::: "memory");   // drains Q1; Q2 stays out
    __builtin_amdgcn_sched_barrier(0);
    __builtin_amdgcn_s_setprio(1);
    MFMA_Q(1, aB, bC);
    __builtin_amdgcn_s_setprio(0);
    __builtin_amdgcn_s_barrier();

    // ---- p2: read Q3 -> aB; stage B1(t+2); MFMA Q2 ----
    READ_AQ(aB, 3, buf);
    stageB(buf, 1, k2);
    __builtin_amdgcn_s_barrier();
    asm volatile("s_waitcnt lgkmcnt(4)" ::: "memory");   // drains Q2; Q3 stays out
    __builtin_amdgcn_sched_barrier(0);
    __builtin_amdgcn_s_setprio(1);
    MFMA_Q(2, aA, bC);
    __builtin_amdgcn_s_setprio(0);
    __builtin_amdgcn_s_barrier();

    // ---- p3: drain tile t+1 DMAs; BARRIER; cross-wave reads of t+1; MFMA Q3 ----
    asm volatile("s_waitcnt vmcnt(4)" ::: "memory");   // B(t+1)+A(t+1) done; B(t+2) out
    __builtin_amdgcn_s_barrier();                      // all waves' t+1 DMAs visible
    __builtin_amdgcn_sched_barrier(0);                 // pin reads below the barrier
    READ_B8(bN, nb);
    READ_AQ(aA, 0, nb);
    asm volatile("s_waitcnt lgkmcnt(12)" ::: "memory"); // drains Q3; 12 new reads stay out
    __builtin_amdgcn_sched_barrier(0);
    __builtin_amdgcn_s_setprio(1);
    MFMA_Q(3, aB, bC);
    __builtin_amdgcn_s_setprio(0);
    __builtin_amdgcn_s_barrier();
  };

  for (int tt2 = 0; tt2 < G1_NT; tt2 += 2) {
    tile_body(tt2,     0, bX, bY);
    tile_body(tt2 + 1, 1, bY, bX);
  }

  // ---- epilogue: drain junk DMA, restage C through LDS (pad 264), coalesced stores ----
  asm volatile("s_waitcnt vmcnt(0)" ::: "memory");
  __syncthreads();

  #pragma unroll
  for (int nj = 0; nj < 4; ++nj) {
    const int colg = n0 + wc*64 + nj*16 + lrow;
    const float bv = bias[colg];
    const int coll = wc*64 + nj*16 + lrow;
    #pragma unroll
    for (int mi = 0; mi < 8; ++mi) {
      #pragma unroll
      for (int r = 0; r < 4; ++r) {
        const int rowl = wr*128 + mi*16 + q*4 + r;   // C/D: col=lane&15, row=quad*4+reg
        ldsAll[rowl*264 + coll] = f2b(silu_f(acc[mi][nj][r] + bv));
      }
    }
  }
  __syncthreads();

  u16* op = (n0 < D_INNER) ? out0 : out1;
  const int colbase = n0 & (D_INNER - 1);
  #pragma unroll
  for (int it = 0; it < 16; ++it) {
    const int f   = it*512 + tid;
    const int row = f >> 5;           // 0..255
    const int ch  = f & 31;           // 16B chunk within 512B row-span
    u16x8 v = *(const u16x8*)(ldsAll + row*264 + ch*8);
    *(u16x8*)(op + (size_t)(m0 + row)*D_INNER + colbase + ch*8) = v;
  }
  #undef READ_AQ
  #undef READ_B8
  #undef MFMA_Q
}

// ------------- MFMA GEMM, double-buffered DMA, 1 barrier/iter (kept for gemm2) -------------
// MODE 0: outf[row*N+col] = f32(acc + bias[col])          (final output, f32)
template<int MODE>
__global__ __launch_bounds__(256) void gemm_bt(const u16* __restrict__ A,
                                               const u16* __restrict__ Bt,
                                               const float* __restrict__ bias,
                                               u16* __restrict__ out0,
                                               u16* __restrict__ out1,
                                               float* __restrict__ outf,
                                               int M, int N, int K, int n_per_xcd){
  __shared__ __align__(16) u16 Asb[2][128*32];   // unpadded: DMA layout constraint
  __shared__ __align__(16) u16 Bsb[2][128*32];
  const int bid = blockIdx.x;
  const int xcd = bid & 7, t2 = bid >> 3;
  const int n0 = (xcd * n_per_xcd + (t2 % n_per_xcd)) * 128;
  const int m0 = (t2 / n_per_xcd) * 128;
  const int t    = threadIdx.x;
  const int wave = t >> 6, lane = t & 63;
  const int wm   = (wave >> 1) * 64, wn = (wave & 1) * 64;
  const int lrow = lane & 15, kq = (lane >> 4) * 8;
  const int srow = lane >> 2;            // staging: row within 16-row block
  const int scol = (lane & 3) * 8;       // staging: 8-u16 chunk within row

  f32x4 acc[4][4];
  #pragma unroll
  for (int i = 0; i < 4; ++i)
    #pragma unroll
    for (int j = 0; j < 4; ++j)
      acc[i][j] = (f32x4){0.f, 0.f, 0.f, 0.f};

  auto stage = [&](int buf, int k0){
    #pragma unroll
    for (int i = 0; i < 2; ++i) {
      int R0 = (wave*2 + i) * 16;        // 0,16,...,112
      gl_lds16(&A [(size_t)(m0 + R0 + srow)*K + k0 + scol], &Asb[buf][R0*32]);
      gl_lds16(&Bt[(size_t)(n0 + R0 + srow)*K + k0 + scol], &Bsb[buf][R0*32]);
    }
  };

  const int KT = K >> 5;
  stage(0, 0);
  __syncthreads();
  for (int kt = 0; kt < KT; ++kt) {
    const int cur = kt & 1;
    if (kt + 1 < KT) stage(1 - cur, (kt + 1) * 32);   // prefetch overlaps compute below
    s16x8 af[4], bfr[4];
    #pragma unroll
    for (int i = 0; i < 4; ++i) af[i]  = *(const s16x8*)&Asb[cur][(wm + i*16 + lrow)*32 + kq];
    #pragma unroll
    for (int j = 0; j < 4; ++j) bfr[j] = *(const s16x8*)&Bsb[cur][(wn + j*16 + lrow)*32 + kq];
    #pragma unroll
    for (int i = 0; i < 4; ++i)
      #pragma unroll
      for (int j = 0; j < 4; ++j)
        acc[i][j] = __builtin_amdgcn_mfma_f32_16x16x32_bf16(af[i], bfr[j], acc[i][j], 0, 0, 0);
    __syncthreads();   // drains prefetch DMA + protects cur buffer reuse
  }

  const int Nh = N >> 1;
  #pragma unroll
  for (int i = 0; i < 4; ++i) {
    #pragma unroll
    for (int j = 0; j < 4; ++j) {
      int col = n0 + wn + j*16 + lrow;
      float bv = bias[col];
      #pragma unroll
      for (int r = 0; r < 4; ++r) {
        int row = m0 + wm + i*16 + (lane >> 4)*4 + r;   // C/D: col=lane&15, row=quad*4+reg
        float v = acc[i][j][r] + bv;
        if (MODE == 0) {
          outf[(size_t)row * N + col] = v;
        } else {
          float s = silu_f(v);
          if (col < Nh) out0[(size_t)row * Nh + col]        = f2b(s);
          else          out1[(size_t)row * Nh + (col - Nh)] = f2b(s);
        }
      }
    }
  }
}

// ------------- B/C projection GEMM with FUSED depthwise conv(3) -------------
__global__ __launch_bounds__(256) void bc_gemm_k(const u16* __restrict__ xs,
                                                 const float* __restrict__ conv_w,
                                                 const float* __restrict__ conv_b,
                                                 const u16* __restrict__ Wt,
                                                 float* __restrict__ partial){
  __shared__ __align__(16) u16 Rsb[130*40];   // raw rows m0-1 .. m0+128
  __shared__ __align__(16) u16 Asb[128*40];   // conv output tile
  __shared__ __align__(16) u16 Wsb[32*40];
  const int kseg = blockIdx.x;
  const int m0   = blockIdx.y * 128;
  const int t    = threadIdx.x;
  const int wave = t >> 6, lane = t & 63;
  const int wm   = wave * 32;
  const int lrow = lane & 15, kq = (lane >> 4) * 8;
  const bool zfirst = (m0 & (SEQ-1)) == 0;          // raw row 0   -> zero (seq start)
  const bool zlast  = ((m0+128) & (SEQ-1)) == 0;    // raw row 129 -> zero (seq end)
  const int ccol = t & 31, r0c = (t >> 5) * 16;     // conv thread mapping

  f32x4 acc[2][2];
  #pragma unroll
  for (int i = 0; i < 2; ++i)
    #pragma unroll
    for (int j = 0; j < 2; ++j)
      acc[i][j] = (f32x4){0.f, 0.f, 0.f, 0.f};

  const int kbase = kseg * (D_INNER / KSEG);
  for (int ks = 0; ks < (D_INNER / KSEG); ks += 32) {
    int k0 = kbase + ks;
    if (t < 128) {
      int f = t * 8;
      int r = f >> 5, c = f & 31;
      *(u16x8*)&Wsb[r*40 + c] = *(const u16x8*)&Wt[(size_t)r*D_INNER + k0 + c];
    }
    #pragma unroll
    for (int i = 0; i < 3; ++i) {
      int idx = i*256 + t;
      if (idx < 520) {
        int r = idx >> 2, c = (idx & 3) * 8;
        u16x8 v = (u16x8){0,0,0,0,0,0,0,0};
        bool zero = (r == 0 && zfirst) || (r == 129 && zlast);
        if (!zero)
          v = *(const u16x8*)&xs[(size_t)(m0 - 1 + r)*D_INNER + k0 + c];
        *(u16x8*)&Rsb[r*40 + c] = v;
      }
    }
    __syncthreads();
    {
      const int dcol = k0 + ccol;
      const float cw0 = conv_w[dcol*3], cw1 = conv_w[dcol*3+1], cw2 = conv_w[dcol*3+2];
      const float cbv = conv_b[dcol];
      #pragma unroll
      for (int r = 0; r < 16; ++r) {
        int rr = r0c + r;
        float v = cw0 * b2f(Rsb[rr*40 + ccol])
                + cw1 * b2f(Rsb[(rr+1)*40 + ccol])
                + cw2 * b2f(Rsb[(rr+2)*40 + ccol]) + cbv;
        Asb[rr*40 + ccol] = f2b(v);
      }
    }
    __syncthreads();
    s16x8 af[2], wf[2];
    #pragma unroll
    for (int i = 0; i < 2; ++i) af[i] = *(const s16x8*)&Asb[(wm + i*16 + lrow)*40 + kq];
    #pragma unroll
    for (int j = 0; j < 2; ++j) wf[j] = *(const s16x8*)&Wsb[(j*16 + lrow)*40 + kq];
    #pragma unroll
    for (int i = 0; i < 2; ++i)
      #pragma unroll
      for (int j = 0; j < 2; ++j)
        acc[i][j] = __builtin_amdgcn_mfma_f32_16x16x32_bf16(af[i], wf[j], acc[i][j], 0, 0, 0);
    __syncthreads();
  }

  #pragma unroll
  for (int i = 0; i < 2; ++i)
    #pragma unroll
    for (int j = 0; j < 2; ++j)
      #pragma unroll
      for (int r = 0; r < 4; ++r) {
        int row = m0 + wm + i*16 + (lane >> 4)*4 + r;
        int col = j*16 + lrow;
        partial[((size_t)kseg * ML + row) * 32 + col] = acc[i][j][r];
      }
}

// ------------- reduce partials + bias + mod -> Bbuf/Cbuf -------------
__global__ __launch_bounds__(256) void bc_reduce_k(const float* __restrict__ partial,
    const float* __restrict__ b_B, const float* __restrict__ B_mod,
    const float* __restrict__ b_C, const float* __restrict__ C_mod,
    float* __restrict__ Bbuf, float* __restrict__ Cbuf){
  int g = blockIdx.x * 256 + threadIdx.x;   // < ML*32
  int row = g >> 5, col = g & 31;
  int b = row >> 11;
  float s = 0.f;
  #pragma unroll
  for (int seg = 0; seg < KSEG; ++seg)
    s += partial[(size_t)seg * ML * 32 + g];
  if (col < 16) Bbuf[(size_t)row*16 + col]      = s + b_B[col]      + B_mod[b*16 + col];
  else          Cbuf[(size_t)row*16 + col - 16] = s + b_C[col - 16] + C_mod[b*16 + col - 16];
}

// ------------- chunked scan, pass 1 (fused conv): local chunk-final states -------------
__global__ __launch_bounds__(256) void state_k(const u16* __restrict__ xs,
    const float* __restrict__ conv_w, const float* __restrict__ conv_b,
    const float* __restrict__ Bbuf, const float* __restrict__ A_log,
    float* __restrict__ hend){
  int c = blockIdx.x, db = blockIdx.y, b = blockIdx.z;
  int d = db*256 + threadIdx.x;

  float Abar[16];
  #pragma unroll
  for (int s = 0; s < 16; ++s)
    Abar[s] = __expf(-0.1f * __expf(A_log[d*16 + s]));
  float h[16];
  #pragma unroll
  for (int s = 0; s < 16; ++s) h[s] = 0.f;

  const float w0 = conv_w[d*3], w1 = conv_w[d*3+1], w2 = conv_w[d*3+2], cb = conv_b[d];
  size_t base = (size_t)b * SEQ * D_INNER + (size_t)c * CH * D_INNER + d;
  const float* Br = Bbuf + ((size_t)b * SEQ + (size_t)c * CH) * 16;
  const int l0 = c * CH;

  float xm = (l0 > 0) ? b2f(xs[base - D_INNER]) : 0.f;
  float x0 = b2f(xs[base]);
  float xp = b2f(xs[base + D_INNER]);
  float Bc[16];
  #pragma unroll
  for (int s = 0; s < 16; ++s) Bc[s] = Br[s];

  for (int l = 0; l < CH; ++l){
    float xq = 0.f;
    if (l0 + l + 2 < SEQ) xq = b2f(xs[base + (size_t)(l+2)*D_INNER]);
    float Bl[16];
    #pragma unroll
    for (int s = 0; s < 16; ++s) Bl[s] = Bc[s];
    if (l < CH-1){
      #pragma unroll
      for (int s = 0; s < 16; ++s) Bc[s] = Br[(l+1)*16 + s];
    }
    float xc = w0*xm + w1*x0 + w2*xp + cb;
    #pragma unroll
    for (int s = 0; s < 16; ++s)
      h[s] = Abar[s]*h[s] + xc*Bl[s];
    xm = x0; x0 = xp; xp = xq;
  }
  float* hp = hend + (((size_t)(b*NCHUNK + c))*D_INNER + d)*16;
  #pragma unroll
  for (int q = 0; q < 4; ++q)
    *(f32x4*)(hp + q*4) = (f32x4){h[q*4], h[q*4+1], h[q*4+2], h[q*4+3]};
}

// ------------- chunked scan, pass 2: prefix across chunks -------------
__global__ __launch_bounds__(256) void prefix_k(const float* __restrict__ hend,
    const float* __restrict__ A_log, float* __restrict__ hin){
  int g = blockIdx.x*256 + threadIdx.x;
  int s = g & 15;
  int d = (g >> 4) & (D_INNER-1);
  int b = g >> 15;
  float decay = __expf(-0.1f * (float)CH * __expf(A_log[d*16 + s]));
  size_t stride = (size_t)D_INNER * 16;
  const float* he = hend + (size_t)b*NCHUNK*stride + (size_t)d*16 + s;
  float*       hi = hin  + (size_t)b*NCHUNK*stride + (size_t)d*16 + s;
  float h = 0.f;
  for (int c0 = 0; c0 < NCHUNK; c0 += 8){
    float v[8];
    #pragma unroll
    for (int i = 0; i < 8; ++i) v[i] = he[(size_t)(c0+i)*stride];
    #pragma unroll
    for (int i = 0; i < 8; ++i){
      hi[(size_t)(c0+i)*stride] = h;
      h = decay*h + v[i];
    }
  }
}

// ------------- chunked scan, pass 3 (fused conv): full scan per chunk from hin -------------
// ybuf MUST NOT alias xs: xs rows l+1/l+2 are read across chunk boundaries by other blocks.
__global__ __launch_bounds__(256) void scan2_k(const u16* __restrict__ xs,
    const u16* __restrict__ gate,
    const float* __restrict__ conv_w, const float* __restrict__ conv_b,
    const float* __restrict__ Bbuf, const float* __restrict__ Cbuf,
    const float* __restrict__ A_log, const float* __restrict__ Dp,
    const float* __restrict__ hin, u16* __restrict__ ybuf){
  int c = blockIdx.x, db = blockIdx.y, b = blockIdx.z;
  int d = db*256 + threadIdx.x;

  float Abar[16];
  #pragma unroll
  for (int s = 0; s < 16; ++s)
    Abar[s] = __expf(-0.1f * __expf(A_log[d*16 + s]));
  float h[16];
  const float* hp = hin + (((size_t)(b*NCHUNK + c))*D_INNER + d)*16;
  #pragma unroll
  for (int q = 0; q < 4; ++q){
    f32x4 v = *(const f32x4*)(hp + q*4);
    #pragma unroll
    for (int j = 0; j < 4; ++j) h[q*4 + j] = v[j];
  }
  float Dd = Dp[d];
  const float w0 = conv_w[d*3], w1 = conv_w[d*3+1], w2 = conv_w[d*3+2], cb = conv_b[d];

  size_t base = (size_t)b * SEQ * D_INNER + (size_t)c * CH * D_INNER + d;
  const float* Br = Bbuf + ((size_t)b * SEQ + (size_t)c * CH) * 16;
  const float* Cr = Cbuf + ((size_t)b * SEQ + (size_t)c * CH) * 16;
  const int l0 = c * CH;

  float xm = (l0 > 0) ? b2f(xs[base - D_INNER]) : 0.f;
  float x0 = b2f(xs[base]);
  float xp = b2f(xs[base + D_INNER]);
  float Bc[16], Cc[16];
  #pragma unroll
  for (int s = 0; s < 16; ++s){ Bc[s] = Br[s]; Cc[s] = Cr[s]; }
  float gcur = b2f(gate[base]);

  for (int l = 0; l < CH; ++l){
    float xq = 0.f;
    if (l0 + l + 2 < SEQ) xq = b2f(xs[base + (size_t)(l+2)*D_INNER]);
    float gnext = (l < CH-1) ? b2f(gate[base + (size_t)(l+1)*D_INNER]) : 0.f;
    float Bl[16], Cl[16];
    #pragma unroll
    for (int s = 0; s < 16; ++s){ Bl[s] = Bc[s]; Cl[s] = Cc[s]; }
    if (l < CH-1){
      #pragma unroll
      for (int s = 0; s < 16; ++s){ Bc[s] = Br[(l+1)*16 + s]; Cc[s] = Cr[(l+1)*16 + s]; }
    }
    float xc = w0*xm + w1*x0 + w2*xp + cb;
    float ya[4] = {0.f, 0.f, 0.f, 0.f};
    #pragma unroll
    for (int s = 0; s < 16; ++s){
      float hv = Abar[s]*h[s] + xc*Bl[s];
      h[s] = hv;
      ya[s & 3] += hv * Cl[s];
    }
    float y = ((ya[0]+ya[1]) + (ya[2]+ya[3]) + Dd*xc) * gcur;
    ybuf[base + (size_t)l*D_INNER] = f2b(y);
    xm = x0; x0 = xp; xp = xq; gcur = gnext;
  }
}

extern "C" void kernel_launch(void* const* d_in, const int* in_sizes, int n_in,
                              void* d_out, int out_size, void* d_ws, size_t ws_size,
                              hipStream_t stream){
  const float* x      = (const float*)d_in[0];
  const float* B_mod  = (const float*)d_in[1];
  const float* C_mod  = (const float*)d_in[2];
  const float* W_in   = (const float*)d_in[3];
  const float* b_in   = (const float*)d_in[4];
  const float* conv_w = (const float*)d_in[5];
  const float* conv_b = (const float*)d_in[6];
  const float* A_log  = (const float*)d_in[7];
  const float* Dp     = (const float*)d_in[8];
  const float* W_B    = (const float*)d_in[9];
  const float* b_B    = (const float*)d_in[10];
  const float* W_C    = (const float*)d_in[11];
  const float* b_C    = (const float*)d_in[12];
  const float* W_out  = (const float*)d_in[13];
  const float* b_out  = (const float*)d_in[14];
  float* out = (float*)d_out;   // reference output dtype is float32

  char* ws = (char*)d_ws;
  size_t off = 0;
  auto alloc = [&](size_t bytes)->char* {
    char* p = ws + off; off += (bytes + 255) & ~(size_t)255; return p;
  };
  u16* Wt_in  = (u16*)alloc((size_t)(2*D_INNER)*D_MODEL*2); // 8.39 MB; dead after gemm1
  u16* Wt_out = (u16*)alloc((size_t)D_MODEL*D_INNER*2);     // 4.2 MB
  u16* xs     = (u16*)alloc((size_t)ML*D_INNER*2);          // silu(x_ssm), conv fused downstream
  u16* gatep  = (u16*)alloc((size_t)ML*D_INNER*2);          // silu(x_res)
  u16* ybuf   = (u16*)alloc((size_t)ML*D_INNER*2);          // scan output
  float* Bbuf = (float*)alloc((size_t)ML*D_STATE*4);
  float* Cbuf = (float*)alloc((size_t)ML*D_STATE*4);
  u16* xbf    = (u16*)alloc((size_t)ML*D_MODEL*2);          // 16.8 MB; dead after gemm1
  float* hin  = (float*)alloc((size_t)BATCH*NCHUNK*D_INNER*16*4);
  u16* Wt_bc  = (u16*)alloc((size_t)32*D_INNER*2);          // 131 KB
  float* hend    = (float*)xbf;    // reuse: xbf dead before state_k
  float* partial = (float*)Wt_in;  // reuse: Wt_in dead after gemm1 (8.39 MB, exact)

  // fused prep: W_in^T, W_out^T, cast(x), Wt_bc (was 4 launches)
  prep_k<<<dim3(10496), 256, 0, stream>>>(W_in, W_out, x, W_B, W_C,
                                          Wt_in, Wt_out, xbf, Wt_bc);

  // gemm1: full-line-staging 4-phase 256x256 (R7 schedule); 512 blocks x 512 threads
  gemm1_k<<<dim3(512), 512, 0, stream>>>(xbf, Wt_in, b_in, xs, gatep);

  // conv(3) fused into bc_gemm/state/scan2 — no conv pass, no xconv tensor
  bc_gemm_k<<<dim3(KSEG, ML/128), 256, 0, stream>>>(xs, conv_w, conv_b, Wt_bc, partial);
  bc_reduce_k<<<dim3((ML*32)/256), 256, 0, stream>>>(
      partial, b_B, B_mod, b_C, C_mod, Bbuf, Cbuf);

  state_k<<<dim3(NCHUNK, D_INNER/256, BATCH), 256, 0, stream>>>(
      xs, conv_w, conv_b, Bbuf, A_log, hend);
  prefix_k<<<dim3((BATCH*D_INNER*16)/256), 256, 0, stream>>>(hend, A_log, hin);
  scan2_k<<<dim3(NCHUNK, D_INNER/256, BATCH), 256, 0, stream>>>(
      xs, gatep, conv_w, conv_b, Bbuf, Cbuf, A_log, Dp, hin, ybuf);

  // gemm2: N-blocks=8 -> 1 per XCD; 512 blocks total
  gemm_bt<0><<<dim3(512), 256, 0, stream>>>(
      ybuf, Wt_out, b_out, nullptr, nullptr, out, ML, D_MODEL, D_INNER, 1);
}

// Round 10
// 359.036 us; speedup vs baseline: 1.1856x; 1.0327x over previous
//
#include <hip/hip_runtime.h>
#include <stdint.h>

#define D_MODEL 1024
#define D_STATE 16
#define D_INNER 2048
#define BATCH   4
#define SEQ     2048
#define ML      (BATCH*SEQ)   // 8192 rows
#define CH      64
#define NCHUNK  (SEQ/CH)      // 32
#define KSEG    8             // K-split for B/C projection GEMM

typedef unsigned short u16;
typedef u16   u16x8  __attribute__((ext_vector_type(8)));
typedef short s16x8  __attribute__((ext_vector_type(8)));
typedef float f32x4  __attribute__((ext_vector_type(4)));

__device__ __forceinline__ float b2f(u16 u){
  union { uint32_t i; float f; } v; v.i = ((uint32_t)u) << 16; return v.f;
}
__device__ __forceinline__ u16 f2b(float f){
  uint32_t x = __float_as_uint(f);
  return (u16)((x + 0x7fffu + ((x >> 16) & 1u)) >> 16);   // RNE
}
__device__ __forceinline__ float silu_f(float v){
  return v / (1.f + __expf(-v));
}
// async global->LDS, 16 B per lane; lds base must be wave-uniform (lane i lands at base + i*16)
__device__ __forceinline__ void gl_lds16(const void* gp, void* lp){
  __builtin_amdgcn_global_load_lds(
      (const __attribute__((address_space(1))) void*)gp,
      (__attribute__((address_space(3))) void*)lp, 16, 0, 0);
}

// ------------- fused prep: W_in^T, W_out^T, cast(x), Wt_bc — one launch -------------
// blocks [0,4096): W_in transpose (R=1024,C=4096); [4096,6144): W_out transpose
// (R=2048,C=1024); [6144,10240): cast x; [10240,10496): bc_wt.
__global__ __launch_bounds__(256) void prep_k(const float* __restrict__ W_in,
                                              const float* __restrict__ W_out,
                                              const float* __restrict__ x,
                                              const float* __restrict__ W_B,
                                              const float* __restrict__ W_C,
                                              u16* __restrict__ Wt_in,
                                              u16* __restrict__ Wt_out,
                                              u16* __restrict__ xbf,
                                              u16* __restrict__ Wt_bc){
  __shared__ float tile[32][33];
  int bb = blockIdx.x;
  if (bb < 6144) {
    const float* in; u16* out; int R, C, bx, by;
    if (bb < 4096) { in = W_in;  out = Wt_in;  R = 1024; C = 4096;
                     bx = (bb & 127) * 32; by = (bb >> 7) * 32; }
    else { bb -= 4096; in = W_out; out = Wt_out; R = 2048; C = 1024;
                     bx = (bb & 31) * 32; by = (bb >> 5) * 32; }
    int tx = threadIdx.x & 31, ty = threadIdx.x >> 5;
    #pragma unroll
    for (int i = 0; i < 32; i += 8)
      tile[ty + i][tx] = in[(size_t)(by + ty + i) * C + bx + tx];
    __syncthreads();
    #pragma unroll
    for (int i = 0; i < 32; i += 8)
      out[(size_t)(bx + ty + i) * R + by + tx] = f2b(tile[tx][ty + i]);
  } else if (bb < 10240) {
    bb -= 6144;
    size_t i = ((size_t)bb * 256 + threadIdx.x) * 8;
    f32x4 a = *(const f32x4*)(x + i);
    f32x4 b = *(const f32x4*)(x + i + 4);
    u16x8 o;
    #pragma unroll
    for (int j = 0; j < 4; ++j){ o[j] = f2b(a[j]); o[4+j] = f2b(b[j]); }
    *(u16x8*)(xbf + i) = o;
  } else {
    bb -= 10240;
    int n = bb >> 3;                         // 0..31
    int k = (bb & 7) * 256 + threadIdx.x;    // 0..2047
    const float* src = (n < 16) ? W_B : W_C;
    Wt_bc[(size_t)n * D_INNER + k] = f2b(src[(size_t)k * 16 + (n & 15)]);
  }
}

// ================= 256x128 GEMM for in_proj — m97-economics, 2 blocks/CU =================
// M=8192, N=4096, K=1024. Tile 256Mx128N, BK=32, 512 threads = 8 waves (4M x 2N),
// per-wave output 64x64 (acc = 64 VGPR). LDS 48KB -> with __launch_bounds__(512,4)
// (VGPR<=128) TWO blocks co-reside per CU: while one block drains at __syncthreads,
// the sibling issues MFMA (m114/m97 implicit overlap — the proven mechanism).
// Simple m97 loop: stage(next) -> read(cur) -> 16 MFMA -> __syncthreads (compiler emits
// the vmcnt/lgkm drain; race-free by construction, single barrier per K-step).
// Staging = full-line requests: gl_lds16 lane j -> row j>>2, chunk (j&3)^(row&3)
// (8 consecutive lanes cover a 128B line). Reads use the same involution
// (frag rows are 16-aligned so row&3 == lrow&3): chunk q^(lrow&3) -> 8 lanes per
// 16B slot-column = conflict-free b128 (verified pattern, R4-R9 conflicts=0).
#define G1_K  1024

__global__ __launch_bounds__(512, 4) void gemm1_k(const u16* __restrict__ A,
                                                  const u16* __restrict__ Bt,
                                                  const float* __restrict__ bias,
                                                  u16* __restrict__ out0,
                                                  u16* __restrict__ out1){
  __shared__ __align__(16) u16 lds[24576];   // 48 KB
  u16* ldsA = lds;              // [2][8192]  256x32 u16 per buf
  u16* ldsB = lds + 16384;      // [2][4096]  128x32 u16 per buf

  const int bid = blockIdx.x;                 // 1024 blocks
  const int xcd = bid & 7, t2 = bid >> 3;
  const int n0 = (xcd*4 + (t2 & 3)) * 128;    // 32 n-blocks, 4 per XCD
  const int m0 = (t2 >> 2) * 256;             // 32 m-blocks

  const int tid  = threadIdx.x;
  const int wave = tid >> 6, lane = tid & 63;
  const int wr = wave >> 1;                   // 0..3: M quarter (64 rows)
  const int wn = (wave & 1) * 64;             // N half (64 cols)
  const int lrow = lane & 15;
  const int q    = lane >> 4;                 // 0..3

  const int cxa  = (q ^ (lrow & 3)) << 3;     // swizzled read chunk (u16 units)
  const int srow = lane >> 2;                 // 0..15
  const int schunk = (((lane & 3) ^ (srow & 3)) << 3);

  auto stageA = [&](int buf, int k0){         // 32 rows/wave = 2 x gl_lds16
    const u16* s = A + (size_t)(m0 + wave*32 + srow) * G1_K + k0 + schunk;
    u16* d = ldsA + buf*8192 + wave*1024;
    gl_lds16(s,                   d);         // rows +0..15
    gl_lds16(s + (size_t)16*G1_K, d + 512);   // rows +16..31
  };
  auto stageB = [&](int buf, int k0){         // 16 rows/wave = 1 x gl_lds16
    const u16* s = Bt + (size_t)(n0 + wave*16 + srow) * G1_K + k0 + schunk;
    gl_lds16(s, ldsB + buf*4096 + wave*512);
  };

  f32x4 acc[4][4];
  #pragma unroll
  for (int i = 0; i < 4; ++i)
    #pragma unroll
    for (int j = 0; j < 4; ++j) acc[i][j] = (f32x4){0.f,0.f,0.f,0.f};

  stageA(0, 0); stageB(0, 0);
  __syncthreads();

  const int KT = G1_K / 32;   // 32 K-steps
  for (int kt = 0; kt < KT; ++kt) {
    const int cur = kt & 1;
    if (kt + 1 < KT) { stageA(1 - cur, (kt+1)*32); stageB(1 - cur, (kt+1)*32); }
    s16x8 af[4], bf[4];
    #pragma unroll
    for (int mi = 0; mi < 4; ++mi)
      af[mi] = *(const s16x8*)&ldsA[cur*8192 + (wr*64 + mi*16 + lrow)*32 + cxa];
    #pragma unroll
    for (int nj = 0; nj < 4; ++nj)
      bf[nj] = *(const s16x8*)&ldsB[cur*4096 + (wn + nj*16 + lrow)*32 + cxa];
    #pragma unroll
    for (int mi = 0; mi < 4; ++mi)
      #pragma unroll
      for (int nj = 0; nj < 4; ++nj)
        acc[mi][nj] = __builtin_amdgcn_mfma_f32_16x16x32_bf16(af[mi], bf[nj], acc[mi][nj], 0,0,0);
    __syncthreads();   // drains own DMAs + protects cur buffer; sibling block covers stall
  }

  // ---- epilogue: bias+silu, restage through LDS in two 128-row halves, 16B stores ----
  u16* op = (n0 < D_INNER) ? out0 : out1;
  const int colbase = n0 & (D_INNER - 1);
  #pragma unroll
  for (int h = 0; h < 2; ++h) {
    __syncthreads();
    if ((wr >> 1) == h) {
      const int rbase = (wr & 1) * 64;
      #pragma unroll
      for (int nj = 0; nj < 4; ++nj) {
        const int col = wn + nj*16 + lrow;
        const float bv = bias[n0 + col];
        #pragma unroll
        for (int mi = 0; mi < 4; ++mi) {
          #pragma unroll
          for (int r = 0; r < 4; ++r) {
            const int row = rbase + mi*16 + q*4 + r;   // C/D: col=lane&15, row=quad*4+reg
            lds[row*136 + col] = f2b(silu_f(acc[mi][nj][r] + bv));
          }
        }
      }
    }
    __syncthreads();
    #pragma unroll
    for (int it = 0; it < 4; ++it) {
      const int f = it*512 + tid;
      const int row = f >> 4, ch = f & 15;   // 16 x 16B chunks per 256B row
      u16x8 v = *(const u16x8*)&lds[row*136 + ch*8];
      *(u16x8*)(op + (size_t)(m0 + h*128 + row)*D_INNER + colbase + ch*8) = v;
    }
  }
}

// ------------- MFMA GEMM, double-buffered DMA, 1 barrier/iter (kept for gemm2) -------------
// MODE 0: outf[row*N+col] = f32(acc + bias[col])          (final output, f32)
template<int MODE>
__global__ __launch_bounds__(256) void gemm_bt(const u16* __restrict__ A,
                                               const u16* __restrict__ Bt,
                                               const float* __restrict__ bias,
                                               u16* __restrict__ out0,
                                               u16* __restrict__ out1,
                                               float* __restrict__ outf,
                                               int M, int N, int K, int n_per_xcd){
  __shared__ __align__(16) u16 Asb[2][128*32];   // unpadded: DMA layout constraint
  __shared__ __align__(16) u16 Bsb[2][128*32];
  const int bid = blockIdx.x;
  const int xcd = bid & 7, t2 = bid >> 3;
  const int n0 = (xcd * n_per_xcd + (t2 % n_per_xcd)) * 128;
  const int m0 = (t2 / n_per_xcd) * 128;
  const int t    = threadIdx.x;
  const int wave = t >> 6, lane = t & 63;
  const int wm   = (wave >> 1) * 64, wn = (wave & 1) * 64;
  const int lrow = lane & 15, kq = (lane >> 4) * 8;
  const int srow = lane >> 2;            // staging: row within 16-row block
  const int scol = (lane & 3) * 8;       // staging: 8-u16 chunk within row

  f32x4 acc[4][4];
  #pragma unroll
  for (int i = 0; i < 4; ++i)
    #pragma unroll
    for (int j = 0; j < 4; ++j)
      acc[i][j] = (f32x4){0.f, 0.f, 0.f, 0.f};

  auto stage = [&](int buf, int k0){
    #pragma unroll
    for (int i = 0; i < 2; ++i) {
      int R0 = (wave*2 + i) * 16;        // 0,16,...,112
      gl_lds16(&A [(size_t)(m0 + R0 + srow)*K + k0 + scol], &Asb[buf][R0*32]);
      gl_lds16(&Bt[(size_t)(n0 + R0 + srow)*K + k0 + scol], &Bsb[buf][R0*32]);
    }
  };

  const int KT = K >> 5;
  stage(0, 0);
  __syncthreads();
  for (int kt = 0; kt < KT; ++kt) {
    const int cur = kt & 1;
    if (kt + 1 < KT) stage(1 - cur, (kt + 1) * 32);   // prefetch overlaps compute below
    s16x8 af[4], bfr[4];
    #pragma unroll
    for (int i = 0; i < 4; ++i) af[i]  = *(const s16x8*)&Asb[cur][(wm + i*16 + lrow)*32 + kq];
    #pragma unroll
    for (int j = 0; j < 4; ++j) bfr[j] = *(const s16x8*)&Bsb[cur][(wn + j*16 + lrow)*32 + kq];
    #pragma unroll
    for (int i = 0; i < 4; ++i)
      #pragma unroll
      for (int j = 0; j < 4; ++j)
        acc[i][j] = __builtin_amdgcn_mfma_f32_16x16x32_bf16(af[i], bfr[j], acc[i][j], 0, 0, 0);
    __syncthreads();   // drains prefetch DMA + protects cur buffer reuse
  }

  const int Nh = N >> 1;
  #pragma unroll
  for (int i = 0; i < 4; ++i) {
    #pragma unroll
    for (int j = 0; j < 4; ++j) {
      int col = n0 + wn + j*16 + lrow;
      float bv = bias[col];
      #pragma unroll
      for (int r = 0; r < 4; ++r) {
        int row = m0 + wm + i*16 + (lane >> 4)*4 + r;   // C/D: col=lane&15, row=quad*4+reg
        float v = acc[i][j][r] + bv;
        if (MODE == 0) {
          outf[(size_t)row * N + col] = v;
        } else {
          float s = silu_f(v);
          if (col < Nh) out0[(size_t)row * Nh + col]        = f2b(s);
          else          out1[(size_t)row * Nh + (col - Nh)] = f2b(s);
        }
      }
    }
  }
}

// ------------- B/C projection GEMM with FUSED depthwise conv(3) -------------
__global__ __launch_bounds__(256) void bc_gemm_k(const u16* __restrict__ xs,
                                                 const float* __restrict__ conv_w,
                                                 const float* __restrict__ conv_b,
                                                 const u16* __restrict__ Wt,
                                                 float* __restrict__ partial){
  __shared__ __align__(16) u16 Rsb[130*40];   // raw rows m0-1 .. m0+128
  __shared__ __align__(16) u16 Asb[128*40];   // conv output tile
  __shared__ __align__(16) u16 Wsb[32*40];
  const int kseg = blockIdx.x;
  const int m0   = blockIdx.y * 128;
  const int t    = threadIdx.x;
  const int wave = t >> 6, lane = t & 63;
  const int wm   = wave * 32;
  const int lrow = lane & 15, kq = (lane >> 4) * 8;
  const bool zfirst = (m0 & (SEQ-1)) == 0;          // raw row 0   -> zero (seq start)
  const bool zlast  = ((m0+128) & (SEQ-1)) == 0;    // raw row 129 -> zero (seq end)
  const int ccol = t & 31, r0c = (t >> 5) * 16;     // conv thread mapping

  f32x4 acc[2][2];
  #pragma unroll
  for (int i = 0; i < 2; ++i)
    #pragma unroll
    for (int j = 0; j < 2; ++j)
      acc[i][j] = (f32x4){0.f, 0.f, 0.f, 0.f};

  const int kbase = kseg * (D_INNER / KSEG);
  for (int ks = 0; ks < (D_INNER / KSEG); ks += 32) {
    int k0 = kbase + ks;
    if (t < 128) {
      int f = t * 8;
      int r = f >> 5, c = f & 31;
      *(u16x8*)&Wsb[r*40 + c] = *(const u16x8*)&Wt[(size_t)r*D_INNER + k0 + c];
    }
    #pragma unroll
    for (int i = 0; i < 3; ++i) {
      int idx = i*256 + t;
      if (idx < 520) {
        int r = idx >> 2, c = (idx & 3) * 8;
        u16x8 v = (u16x8){0,0,0,0,0,0,0,0};
        bool zero = (r == 0 && zfirst) || (r == 129 && zlast);
        if (!zero)
          v = *(const u16x8*)&xs[(size_t)(m0 - 1 + r)*D_INNER + k0 + c];
        *(u16x8*)&Rsb[r*40 + c] = v;
      }
    }
    __syncthreads();
    {
      const int dcol = k0 + ccol;
      const float cw0 = conv_w[dcol*3], cw1 = conv_w[dcol*3+1], cw2 = conv_w[dcol*3+2];
      const float cbv = conv_b[dcol];
      #pragma unroll
      for (int r = 0; r < 16; ++r) {
        int rr = r0c + r;
        float v = cw0 * b2f(Rsb[rr*40 + ccol])
                + cw1 * b2f(Rsb[(rr+1)*40 + ccol])
                + cw2 * b2f(Rsb[(rr+2)*40 + ccol]) + cbv;
        Asb[rr*40 + ccol] = f2b(v);
      }
    }
    __syncthreads();
    s16x8 af[2], wf[2];
    #pragma unroll
    for (int i = 0; i < 2; ++i) af[i] = *(const s16x8*)&Asb[(wm + i*16 + lrow)*40 + kq];
    #pragma unroll
    for (int j = 0; j < 2; ++j) wf[j] = *(const s16x8*)&Wsb[(j*16 + lrow)*40 + kq];
    #pragma unroll
    for (int i = 0; i < 2; ++i)
      #pragma unroll
      for (int j = 0; j < 2; ++j)
        acc[i][j] = __builtin_amdgcn_mfma_f32_16x16x32_bf16(af[i], wf[j], acc[i][j], 0, 0, 0);
    __syncthreads();
  }

  #pragma unroll
  for (int i = 0; i < 2; ++i)
    #pragma unroll
    for (int j = 0; j < 2; ++j)
      #pragma unroll
      for (int r = 0; r < 4; ++r) {
        int row = m0 + wm + i*16 + (lane >> 4)*4 + r;
        int col = j*16 + lrow;
        partial[((size_t)kseg * ML + row) * 32 + col] = acc[i][j][r];
      }
}

// ------------- reduce partials + bias + mod -> Bbuf/Cbuf -------------
__global__ __launch_bounds__(256) void bc_reduce_k(const float* __restrict__ partial,
    const float* __restrict__ b_B, const float* __restrict__ B_mod,
    const float* __restrict__ b_C, const float* __restrict__ C_mod,
    float* __restrict__ Bbuf, float* __restrict__ Cbuf){
  int g = blockIdx.x * 256 + threadIdx.x;   // < ML*32
  int row = g >> 5, col = g & 31;
  int b = row >> 11;
  float s = 0.f;
  #pragma unroll
  for (int seg = 0; seg < KSEG; ++seg)
    s += partial[(size_t)seg * ML * 32 + g];
  if (col < 16) Bbuf[(size_t)row*16 + col]      = s + b_B[col]      + B_mod[b*16 + col];
  else          Cbuf[(size_t)row*16 + col - 16] = s + b_C[col - 16] + C_mod[b*16 + col - 16];
}

// ------------- chunked scan, pass 1 (fused conv): local chunk-final states -------------
__global__ __launch_bounds__(256) void state_k(const u16* __restrict__ xs,
    const float* __restrict__ conv_w, const float* __restrict__ conv_b,
    const float* __restrict__ Bbuf, const float* __restrict__ A_log,
    float* __restrict__ hend){
  int c = blockIdx.x, db = blockIdx.y, b = blockIdx.z;
  int d = db*256 + threadIdx.x;

  float Abar[16];
  #pragma unroll
  for (int s = 0; s < 16; ++s)
    Abar[s] = __expf(-0.1f * __expf(A_log[d*16 + s]));
  float h[16];
  #pragma unroll
  for (int s = 0; s < 16; ++s) h[s] = 0.f;

  const float w0 = conv_w[d*3], w1 = conv_w[d*3+1], w2 = conv_w[d*3+2], cb = conv_b[d];
  size_t base = (size_t)b * SEQ * D_INNER + (size_t)c * CH * D_INNER + d;
  const float* Br = Bbuf + ((size_t)b * SEQ + (size_t)c * CH) * 16;
  const int l0 = c * CH;

  float xm = (l0 > 0) ? b2f(xs[base - D_INNER]) : 0.f;
  float x0 = b2f(xs[base]);
  float xp = b2f(xs[base + D_INNER]);
  float Bc[16];
  #pragma unroll
  for (int s = 0; s < 16; ++s) Bc[s] = Br[s];

  for (int l = 0; l < CH; ++l){
    float xq = 0.f;
    if (l0 + l + 2 < SEQ) xq = b2f(xs[base + (size_t)(l+2)*D_INNER]);
    float Bl[16];
    #pragma unroll
    for (int s = 0; s < 16; ++s) Bl[s] = Bc[s];
    if (l < CH-1){
      #pragma unroll
      for (int s = 0; s < 16; ++s) Bc[s] = Br[(l+1)*16 + s];
    }
    float xc = w0*xm + w1*x0 + w2*xp + cb;
    #pragma unroll
    for (int s = 0; s < 16; ++s)
      h[s] = Abar[s]*h[s] + xc*Bl[s];
    xm = x0; x0 = xp; xp = xq;
  }
  float* hp = hend + (((size_t)(b*NCHUNK + c))*D_INNER + d)*16;
  #pragma unroll
  for (int q = 0; q < 4; ++q)
    *(f32x4*)(hp + q*4) = (f32x4){h[q*4], h[q*4+1], h[q*4+2], h[q*4+3]};
}

// ------------- chunked scan, pass 2: prefix across chunks -------------
__global__ __launch_bounds__(256) void prefix_k(const float* __restrict__ hend,
    const float* __restrict__ A_log, float* __restrict__ hin){
  int g = blockIdx.x*256 + threadIdx.x;
  int s = g & 15;
  int d = (g >> 4) & (D_INNER-1);
  int b = g >> 15;
  float decay = __expf(-0.1f * (float)CH * __expf(A_log[d*16 + s]));
  size_t stride = (size_t)D_INNER * 16;
  const float* he = hend + (size_t)b*NCHUNK*stride + (size_t)d*16 + s;
  float*       hi = hin  + (size_t)b*NCHUNK*stride + (size_t)d*16 + s;
  float h = 0.f;
  for (int c0 = 0; c0 < NCHUNK; c0 += 8){
    float v[8];
    #pragma unroll
    for (int i = 0; i < 8; ++i) v[i] = he[(size_t)(c0+i)*stride];
    #pragma unroll
    for (int i = 0; i < 8; ++i){
      hi[(size_t)(c0+i)*stride] = h;
      h = decay*h + v[i];
    }
  }
}

// ------------- chunked scan, pass 3 (fused conv): full scan per chunk from hin -------------
// ybuf MUST NOT alias xs: xs rows l+1/l+2 are read across chunk boundaries by other blocks.
__global__ __launch_bounds__(256) void scan2_k(const u16* __restrict__ xs,
    const u16* __restrict__ gate,
    const float* __restrict__ conv_w, const float* __restrict__ conv_b,
    const float* __restrict__ Bbuf, const float* __restrict__ Cbuf,
    const float* __restrict__ A_log, const float* __restrict__ Dp,
    const float* __restrict__ hin, u16* __restrict__ ybuf){
  int c = blockIdx.x, db = blockIdx.y, b = blockIdx.z;
  int d = db*256 + threadIdx.x;

  float Abar[16];
  #pragma unroll
  for (int s = 0; s < 16; ++s)
    Abar[s] = __expf(-0.1f * __expf(A_log[d*16 + s]));
  float h[16];
  const float* hp = hin + (((size_t)(b*NCHUNK + c))*D_INNER + d)*16;
  #pragma unroll
  for (int q = 0; q < 4; ++q){
    f32x4 v = *(const f32x4*)(hp + q*4);
    #pragma unroll
    for (int j = 0; j < 4; ++j) h[q*4 + j] = v[j];
  }
  float Dd = Dp[d];
  const float w0 = conv_w[d*3], w1 = conv_w[d*3+1], w2 = conv_w[d*3+2], cb = conv_b[d];

  size_t base = (size_t)b * SEQ * D_INNER + (size_t)c * CH * D_INNER + d;
  const float* Br = Bbuf + ((size_t)b * SEQ + (size_t)c * CH) * 16;
  const float* Cr = Cbuf + ((size_t)b * SEQ + (size_t)c * CH) * 16;
  const int l0 = c * CH;

  float xm = (l0 > 0) ? b2f(xs[base - D_INNER]) : 0.f;
  float x0 = b2f(xs[base]);
  float xp = b2f(xs[base + D_INNER]);
  float Bc[16], Cc[16];
  #pragma unroll
  for (int s = 0; s < 16; ++s){ Bc[s] = Br[s]; Cc[s] = Cr[s]; }
  float gcur = b2f(gate[base]);

  for (int l = 0; l < CH; ++l){
    float xq = 0.f;
    if (l0 + l + 2 < SEQ) xq = b2f(xs[base + (size_t)(l+2)*D_INNER]);
    float gnext = (l < CH-1) ? b2f(gate[base + (size_t)(l+1)*D_INNER]) : 0.f;
    float Bl[16], Cl[16];
    #pragma unroll
    for (int s = 0; s < 16; ++s){ Bl[s] = Bc[s]; Cl[s] = Cc[s]; }
    if (l < CH-1){
      #pragma unroll
      for (int s = 0; s < 16; ++s){ Bc[s] = Br[(l+1)*16 + s]; Cc[s] = Cr[(l+1)*16 + s]; }
    }
    float xc = w0*xm + w1*x0 + w2*xp + cb;
    float ya[4] = {0.f, 0.f, 0.f, 0.f};
    #pragma unroll
    for (int s = 0; s < 16; ++s){
      float hv = Abar[s]*h[s] + xc*Bl[s];
      h[s] = hv;
      ya[s & 3] += hv * Cl[s];
    }
    float y = ((ya[0]+ya[1]) + (ya[2]+ya[3]) + Dd*xc) * gcur;
    ybuf[base + (size_t)l*D_INNER] = f2b(y);
    xm = x0; x0 = xp; xp = xq; gcur = gnext;
  }
}

extern "C" void kernel_launch(void* const* d_in, const int* in_sizes, int n_in,
                              void* d_out, int out_size, void* d_ws, size_t ws_size,
                              hipStream_t stream){
  const float* x      = (const float*)d_in[0];
  const float* B_mod  = (const float*)d_in[1];
  const float* C_mod  = (const float*)d_in[2];
  const float* W_in   = (const float*)d_in[3];
  const float* b_in   = (const float*)d_in[4];
  const float* conv_w = (const float*)d_in[5];
  const float* conv_b = (const float*)d_in[6];
  const float* A_log  = (const float*)d_in[7];
  const float* Dp     = (const float*)d_in[8];
  const float* W_B    = (const float*)d_in[9];
  const float* b_B    = (const float*)d_in[10];
  const float* W_C    = (const float*)d_in[11];
  const float* b_C    = (const float*)d_in[12];
  const float* W_out  = (const float*)d_in[13];
  const float* b_out  = (const float*)d_in[14];
  float* out = (float*)d_out;   // reference output dtype is float32

  char* ws = (char*)d_ws;
  size_t off = 0;
  auto alloc = [&](size_t bytes)->char* {
    char* p = ws + off; off += (bytes + 255) & ~(size_t)255; return p;
  };
  u16* Wt_in  = (u16*)alloc((size_t)(2*D_INNER)*D_MODEL*2); // 8.39 MB; dead after gemm1
  u16* Wt_out = (u16*)alloc((size_t)D_MODEL*D_INNER*2);     // 4.2 MB
  u16* xs     = (u16*)alloc((size_t)ML*D_INNER*2);          // silu(x_ssm), conv fused downstream
  u16* gatep  = (u16*)alloc((size_t)ML*D_INNER*2);          // silu(x_res)
  u16* ybuf   = (u16*)alloc((size_t)ML*D_INNER*2);          // scan output
  float* Bbuf = (float*)alloc((size_t)ML*D_STATE*4);
  float* Cbuf = (float*)alloc((size_t)ML*D_STATE*4);
  u16* xbf    = (u16*)alloc((size_t)ML*D_MODEL*2);          // 16.8 MB; dead after gemm1
  float* hin  = (float*)alloc((size_t)BATCH*NCHUNK*D_INNER*16*4);
  u16* Wt_bc  = (u16*)alloc((size_t)32*D_INNER*2);          // 131 KB
  float* hend    = (float*)xbf;    // reuse: xbf dead before state_k
  float* partial = (float*)Wt_in;  // reuse: Wt_in dead after gemm1 (8.39 MB, exact)

  // fused prep: W_in^T, W_out^T, cast(x), Wt_bc (was 4 launches)
  prep_k<<<dim3(10496), 256, 0, stream>>>(W_in, W_out, x, W_B, W_C,
                                          Wt_in, Wt_out, xbf, Wt_bc);

  // gemm1: 256x128 tile, BK=32, m97-economics, 2 blocks/CU; 1024 blocks x 512 threads
  gemm1_k<<<dim3(1024), 512, 0, stream>>>(xbf, Wt_in, b_in, xs, gatep);

  // conv(3) fused into bc_gemm/state/scan2 — no conv pass, no xconv tensor
  bc_gemm_k<<<dim3(KSEG, ML/128), 256, 0, stream>>>(xs, conv_w, conv_b, Wt_bc, partial);
  bc_reduce_k<<<dim3((ML*32)/256), 256, 0, stream>>>(
      partial, b_B, B_mod, b_C, C_mod, Bbuf, Cbuf);

  state_k<<<dim3(NCHUNK, D_INNER/256, BATCH), 256, 0, stream>>>(
      xs, conv_w, conv_b, Bbuf, A_log, hend);
  prefix_k<<<dim3((BATCH*D_INNER*16)/256), 256, 0, stream>>>(hend, A_log, hin);
  scan2_k<<<dim3(NCHUNK, D_INNER/256, BATCH), 256, 0, stream>>>(
      xs, gatep, conv_w, conv_b, Bbuf, Cbuf, A_log, Dp, hin, ybuf);

  // gemm2: N-blocks=8 -> 1 per XCD; 512 blocks total
  gemm_bt<0><<<dim3(512), 256, 0, stream>>>(
      ybuf, Wt_out, b_out, nullptr, nullptr, out, ML, D_MODEL, D_INNER, 1);
}